// Round 1
// baseline (444.556 us; speedup 1.0000x reference)
//
#include <hip/hip_runtime.h>

// Shapes (fixed by setup_inputs): B=8, C=64, H=W=64, CTX=64, SF=2
// f1 = prelu(conv3x3(ctx, c1_w)+c1_b)          : [8][64][64][64]
// f2 = prelu(conv3x3(f1, c2_w)+c2_b)           : [8][32][64][64]
// mask = conv1x1(f2, kp_w)+kp_b  (fused, never materialized)
// out[b][c][2w+q][2h+p] = sum_k softmax_k(mask[c*36+k*4+p*2+q]) * x_edge[b][c][h+dy-1][w+dx-1]

// ---------------- conv 3x3 + bias + prelu ----------------
// Grid: B*64 blocks, block = (b, h). 256 threads: lane w = t&63, group cg = t>>6.
// Each thread computes CPT output channels at its (h, w).
template <int CIN, int COUT, int CPT>
__global__ __launch_bounds__(256) void k_conv3x3(
    const float* __restrict__ x,      // [B][CIN][64][64]
    const float* __restrict__ wgt,    // [COUT][CIN][3][3]
    const float* __restrict__ bias,   // [COUT]
    const float* __restrict__ alpha,  // [COUT]
    float* __restrict__ y)            // [B][COUT][64][64]
{
    const int b = blockIdx.x >> 6;
    const int h = blockIdx.x & 63;
    __shared__ float lds[3][CIN][66];   // rows h-1..h+1, w padded by 1 (zeros)
    const int t = threadIdx.x;

    for (int idx = t; idx < 3 * CIN * 64; idx += 256) {
        int r  = idx / (CIN * 64);
        int ci = (idx / 64) % CIN;
        int w  = idx & 63;
        int hh = h + r - 1;
        float v = 0.f;
        if (hh >= 0 && hh < 64)
            v = x[((b * CIN + ci) * 64 + hh) * 64 + w];
        lds[r][ci][w + 1] = v;
    }
    if (t < 3 * CIN) {   // 3*CIN <= 192 < 256
        int r = t / CIN, ci = t % CIN;
        lds[r][ci][0]  = 0.f;
        lds[r][ci][65] = 0.f;
    }
    __syncthreads();

    const int w   = t & 63;
    const int cg  = __builtin_amdgcn_readfirstlane(t >> 6);  // wave-uniform
    const int co0 = cg * CPT;

    float acc[CPT];
#pragma unroll
    for (int i = 0; i < CPT; ++i) acc[i] = bias[co0 + i];

    for (int ci = 0; ci < CIN; ++ci) {
        float v[3][3];
#pragma unroll
        for (int ky = 0; ky < 3; ++ky) {
            v[ky][0] = lds[ky][ci][w];
            v[ky][1] = lds[ky][ci][w + 1];
            v[ky][2] = lds[ky][ci][w + 2];
        }
#pragma unroll
        for (int co = 0; co < CPT; ++co) {
            const float* wp = &wgt[((co0 + co) * CIN + ci) * 9];
            float a = acc[co];
            a = fmaf(wp[0], v[0][0], a);
            a = fmaf(wp[1], v[0][1], a);
            a = fmaf(wp[2], v[0][2], a);
            a = fmaf(wp[3], v[1][0], a);
            a = fmaf(wp[4], v[1][1], a);
            a = fmaf(wp[5], v[1][2], a);
            a = fmaf(wp[6], v[2][0], a);
            a = fmaf(wp[7], v[2][1], a);
            a = fmaf(wp[8], v[2][2], a);
            acc[co] = a;
        }
    }

#pragma unroll
    for (int co = 0; co < CPT; ++co) {
        float a  = acc[co];
        float al = alpha[co0 + co];
        float o  = (a > 0.f) ? a : al * a;
        y[((b * COUT + co0 + co) * 64 + h) * 64 + w] = o;
    }
}

// ---------------- fused 1x1-conv + softmax + upsample ----------------
// Grid: B*64 blocks, block = (b, w). 256 threads: lane h = t&63, group cg = t>>6.
// Each thread handles 16 channels c for its (h, w) pixel.
__global__ __launch_bounds__(256) void k_upsample(
    const float* __restrict__ f2,    // [B][32][64][64]
    const float* __restrict__ kpw,   // [2304][32]
    const float* __restrict__ kpb,   // [2304]
    const float* __restrict__ xlow,  // [B][64][64][64]
    float* __restrict__ out)         // [B][64][128][128]
{
    const int b = blockIdx.x >> 6;
    const int w = blockIdx.x & 63;
    __shared__ float F[32][64];      // F[ci][h] for this (b, w) column
    const int t = threadIdx.x;

    for (int idx = t; idx < 32 * 64; idx += 256) {
        int ci = idx >> 6, h = idx & 63;
        F[ci][h] = f2[((b * 32 + ci) * 64 + h) * 64 + w];
    }
    __syncthreads();

    const int h  = t & 63;
    const int cg = __builtin_amdgcn_readfirstlane(t >> 6);  // wave-uniform

    for (int cc = 0; cc < 16; ++cc) {
        const int c = cg * 16 + cc;

        // mask rows for this c: rows c*36 .. c*36+35, each a K=32 dot
        float acc[36];
#pragma unroll
        for (int r = 0; r < 36; ++r) acc[r] = kpb[c * 36 + r];

        const float4* wp4 = (const float4*)(kpw + c * 36 * 32);
        for (int ci4 = 0; ci4 < 8; ++ci4) {
            float f0 = F[ci4 * 4 + 0][h];
            float f1 = F[ci4 * 4 + 1][h];
            float f2v = F[ci4 * 4 + 2][h];
            float f3 = F[ci4 * 4 + 3][h];
#pragma unroll
            for (int r = 0; r < 36; ++r) {
                float4 wv = wp4[r * 8 + ci4];
                acc[r] = fmaf(wv.x, f0,
                         fmaf(wv.y, f1,
                         fmaf(wv.z, f2v,
                         fmaf(wv.w, f3, acc[r]))));
            }
        }

        // 9 neighbors of x_low with edge clamp
        float neigh[9];
#pragma unroll
        for (int k = 0; k < 9; ++k) {
            int dy = k / 3 - 1, dx = k % 3 - 1;
            int hh = min(max(h + dy, 0), 63);
            int ww = min(max(w + dx, 0), 63);
            neigh[k] = xlow[((b * 64 + c) * 64 + hh) * 64 + ww];
        }

        // softmax over k per (p,q), weighted sum, transposed store
#pragma unroll
        for (int q = 0; q < 2; ++q) {
            float2 o2;
#pragma unroll
            for (int p = 0; p < 2; ++p) {
                const int pq = p * 2 + q;
                float m = acc[pq];
#pragma unroll
                for (int k = 1; k < 9; ++k) m = fmaxf(m, acc[k * 4 + pq]);
                float s = 0.f, ov = 0.f;
#pragma unroll
                for (int k = 0; k < 9; ++k) {
                    float e = __expf(acc[k * 4 + pq] - m);
                    s += e;
                    ov = fmaf(e, neigh[k], ov);
                }
                ((float*)&o2)[p] = ov / s;
            }
            // out[b][c][2w+q][2h + p], p contiguous -> float2, lanes h -> coalesced
            *(float2*)&out[((b * 64 + c) * 128 + (2 * w + q)) * 128 + 2 * h] = o2;
        }
    }
}

extern "C" void kernel_launch(void* const* d_in, const int* in_sizes, int n_in,
                              void* d_out, int out_size, void* d_ws, size_t ws_size,
                              hipStream_t stream) {
    const float* x_low = (const float*)d_in[0];
    const float* ctx   = (const float*)d_in[1];
    const float* c1_w  = (const float*)d_in[2];
    const float* c1_b  = (const float*)d_in[3];
    const float* p1_a  = (const float*)d_in[4];
    const float* c2_w  = (const float*)d_in[5];
    const float* c2_b  = (const float*)d_in[6];
    const float* p2_a  = (const float*)d_in[7];
    const float* kp_w  = (const float*)d_in[8];
    const float* kp_b  = (const float*)d_in[9];
    float* out = (float*)d_out;

    float* f1 = (float*)d_ws;                  // 8*64*64*64 floats = 8 MB
    float* f2 = f1 + 8 * 64 * 64 * 64;         // 8*32*64*64 floats = 4 MB

    k_conv3x3<64, 64, 16><<<8 * 64, 256, 0, stream>>>(ctx, c1_w, c1_b, p1_a, f1);
    k_conv3x3<64, 32, 8><<<8 * 64, 256, 0, stream>>>(f1, c2_w, c2_b, p2_a, f2);
    k_upsample<<<8 * 64, 256, 0, stream>>>(f2, kp_w, kp_b, x_low, out);
}

// Round 5
// 417.484 us; speedup vs baseline: 1.0648x; 1.0648x over previous
//
#include <hip/hip_runtime.h>

// Shapes fixed by setup_inputs: B=8, C=64, H=W=64, CTX=64, SF=2
// f1 = prelu(conv3x3(ctx)+b1)   : [8][64][64][64]   (ws)
// f2 = prelu(conv3x3(f1)+b2)    : [8][32][64][64]   (ws)
// out = fused 1x1conv(kp) + softmax(9 taps) + upsample (mask never materialized)
// Structure is identical to the round-1 version that passed the full harness
// (incl. graph-replay re-validation); only grid splits changed for occupancy.

// ---------------- conv 3x3 + bias + prelu ----------------
// grid(2, 64, 8) = (s, h, b); 256 threads: lane w = t&63, wave cg = t>>6.
// Wave computes CPT channels starting at (s*4+cg)*CPT.
template <int CIN, int COUT, int CPT>
__global__ __launch_bounds__(256) void k_conv3x3(
    const float* __restrict__ x,      // [B][CIN][64][64]
    const float* __restrict__ wgt,    // [COUT][CIN][3][3]
    const float* __restrict__ bias,   // [COUT]
    const float* __restrict__ alpha,  // [COUT]
    float* __restrict__ y)            // [B][COUT][64][64]
{
    const int s = blockIdx.x;
    const int h = blockIdx.y;
    const int b = blockIdx.z;
    __shared__ float lds[3][CIN][66];   // rows h-1..h+1, w padded by 1 (zeros)
    const int t = threadIdx.x;

    for (int idx = t; idx < 3 * CIN * 64; idx += 256) {
        int r  = idx / (CIN * 64);
        int ci = (idx >> 6) % CIN;
        int w  = idx & 63;
        int hh = h + r - 1;
        float v = 0.f;
        if (hh >= 0 && hh < 64)
            v = x[((b * CIN + ci) * 64 + hh) * 64 + w];
        lds[r][ci][w + 1] = v;
    }
    for (int idx = t; idx < 3 * CIN; idx += 256) {
        int r = idx / CIN, ci = idx % CIN;
        lds[r][ci][0]  = 0.f;
        lds[r][ci][65] = 0.f;
    }
    __syncthreads();

    const int w   = t & 63;
    const int cg  = __builtin_amdgcn_readfirstlane(t >> 6);  // wave-uniform
    const int co0 = (s * 4 + cg) * CPT;

    float acc[CPT];
#pragma unroll
    for (int i = 0; i < CPT; ++i) acc[i] = bias[co0 + i];

    for (int ci = 0; ci < CIN; ++ci) {
        float v[3][3];
#pragma unroll
        for (int ky = 0; ky < 3; ++ky) {
            v[ky][0] = lds[ky][ci][w];
            v[ky][1] = lds[ky][ci][w + 1];
            v[ky][2] = lds[ky][ci][w + 2];
        }
#pragma unroll
        for (int co = 0; co < CPT; ++co) {
            const float* wp = &wgt[((co0 + co) * CIN + ci) * 9];
            float a = acc[co];
            a = fmaf(wp[0], v[0][0], a);
            a = fmaf(wp[1], v[0][1], a);
            a = fmaf(wp[2], v[0][2], a);
            a = fmaf(wp[3], v[1][0], a);
            a = fmaf(wp[4], v[1][1], a);
            a = fmaf(wp[5], v[1][2], a);
            a = fmaf(wp[6], v[2][0], a);
            a = fmaf(wp[7], v[2][1], a);
            a = fmaf(wp[8], v[2][2], a);
            acc[co] = a;
        }
    }

#pragma unroll
    for (int co = 0; co < CPT; ++co) {
        float a  = acc[co];
        float al = alpha[co0 + co];
        float o  = (a > 0.f) ? a : al * a;
        y[((b * COUT + co0 + co) * 64 + h) * 64 + w] = o;
    }
}

// ---------------- fused 1x1-conv + softmax + upsample ----------------
// grid(4, 64, 8) = (cq, w, b); 256 threads: lane h = t&63, wave cg = t>>6.
// Each thread handles 4 channels c = (cq*4+cg)*4 + cc at its (h, w) pixel.
__global__ __launch_bounds__(256) void k_upsample(
    const float* __restrict__ f2,    // [B][32][64][64]
    const float* __restrict__ kpw,   // [2304][32]
    const float* __restrict__ kpb,   // [2304]
    const float* __restrict__ xlow,  // [B][64][64][64]
    float* __restrict__ out)         // [B][64][128][128]
{
    const int cq = blockIdx.x;
    const int w  = blockIdx.y;
    const int b  = blockIdx.z;
    __shared__ float F[32][64];      // F[ci][h] for this (b, w) column
    const int t = threadIdx.x;

    for (int idx = t; idx < 32 * 64; idx += 256) {
        int ci = idx >> 6, h = idx & 63;
        F[ci][h] = f2[((b * 32 + ci) * 64 + h) * 64 + w];
    }
    __syncthreads();

    const int h  = t & 63;
    const int cg = __builtin_amdgcn_readfirstlane(t >> 6);  // wave-uniform

    for (int cc = 0; cc < 4; ++cc) {
        const int c = (cq * 4 + cg) * 4 + cc;

        // mask rows for this c: rows c*36 .. c*36+35, each a K=32 dot
        float acc[36];
#pragma unroll
        for (int r = 0; r < 36; ++r) acc[r] = kpb[c * 36 + r];

        const float4* wp4 = (const float4*)(kpw + c * 36 * 32);
        for (int ci4 = 0; ci4 < 8; ++ci4) {
            float f0  = F[ci4 * 4 + 0][h];
            float f1  = F[ci4 * 4 + 1][h];
            float f2v = F[ci4 * 4 + 2][h];
            float f3  = F[ci4 * 4 + 3][h];
#pragma unroll
            for (int r = 0; r < 36; ++r) {
                float4 wv = wp4[r * 8 + ci4];
                acc[r] = fmaf(wv.x, f0,
                         fmaf(wv.y, f1,
                         fmaf(wv.z, f2v,
                         fmaf(wv.w, f3, acc[r]))));
            }
        }

        // 9 neighbors of x_low with edge clamp
        float neigh[9];
#pragma unroll
        for (int k = 0; k < 9; ++k) {
            int dy = k / 3 - 1, dx = k % 3 - 1;
            int hh = min(max(h + dy, 0), 63);
            int ww = min(max(w + dx, 0), 63);
            neigh[k] = xlow[((b * 64 + c) * 64 + hh) * 64 + ww];
        }

        // softmax over k per (p,q), weighted sum, transposed store
#pragma unroll
        for (int q = 0; q < 2; ++q) {
            float2 o2;
#pragma unroll
            for (int p = 0; p < 2; ++p) {
                const int pq = p * 2 + q;
                float m = acc[pq];
#pragma unroll
                for (int k = 1; k < 9; ++k) m = fmaxf(m, acc[k * 4 + pq]);
                float ssum = 0.f, ov = 0.f;
#pragma unroll
                for (int k = 0; k < 9; ++k) {
                    float e = __expf(acc[k * 4 + pq] - m);
                    ssum += e;
                    ov = fmaf(e, neigh[k], ov);
                }
                ((float*)&o2)[p] = ov / ssum;
            }
            // out[b][c][2w+q][2h+p]; p contiguous -> float2, lanes h -> coalesced
            *(float2*)&out[((b * 64 + c) * 128 + (2 * w + q)) * 128 + 2 * h] = o2;
        }
    }
}

extern "C" void kernel_launch(void* const* d_in, const int* in_sizes, int n_in,
                              void* d_out, int out_size, void* d_ws, size_t ws_size,
                              hipStream_t stream) {
    (void)in_sizes; (void)n_in; (void)out_size; (void)ws_size;
    const float* x_low = (const float*)d_in[0];
    const float* ctx   = (const float*)d_in[1];
    const float* c1_w  = (const float*)d_in[2];
    const float* c1_b  = (const float*)d_in[3];
    const float* p1_a  = (const float*)d_in[4];
    const float* c2_w  = (const float*)d_in[5];
    const float* c2_b  = (const float*)d_in[6];
    const float* p2_a  = (const float*)d_in[7];
    const float* kp_w  = (const float*)d_in[8];
    const float* kp_b  = (const float*)d_in[9];
    float* out = (float*)d_out;

    float* f1 = (float*)d_ws;                  // 8*64*64*64 floats = 8 MB
    float* f2 = f1 + 8 * 64 * 64 * 64;         // 8*32*64*64 floats = 4 MB

    k_conv3x3<64, 64, 8><<<dim3(2, 64, 8), 256, 0, stream>>>(ctx, c1_w, c1_b, p1_a, f1);
    k_conv3x3<64, 32, 4><<<dim3(2, 64, 8), 256, 0, stream>>>(f1, c2_w, c2_b, p2_a, f2);
    k_upsample<<<dim3(4, 64, 8), 256, 0, stream>>>(f2, kp_w, kp_b, x_low, out);
}

// Round 6
// 343.425 us; speedup vs baseline: 1.2945x; 1.2156x over previous
//
#include <hip/hip_runtime.h>

// Shapes fixed by setup_inputs: B=8, C=64, H=W=64, CTX=64, SF=2
// f1 = prelu(conv3x3(ctx)+b1)   : [8][64][64][64]   (ws)
// f2 = prelu(conv3x3(f1)+b2)    : [8][32][64][64]   (ws)
// out = fused 1x1conv(kp) + softmax(9 taps) + upsample (mask never materialized)
// Proven 3-kernel fp32 structure (R1/R5 passed full harness). This round:
// 512-thread blocks (more waves under the same LDS cap) + launch_bounds to
// keep the 36-entry accumulator in VGPRs instead of scratch.

// ---------------- conv 3x3 + bias + prelu ----------------
// grid(64, 8) = (h, b); 512 threads = 8 waves: lane w = t&63, wave cg = t>>6.
// Wave computes CPT channels starting at cg*CPT (8 waves cover COUT).
template <int CIN, int COUT, int CPT>
__global__ __launch_bounds__(512, 4) void k_conv3x3(
    const float* __restrict__ x,      // [B][CIN][64][64]
    const float* __restrict__ wgt,    // [COUT][CIN][3][3]
    const float* __restrict__ bias,   // [COUT]
    const float* __restrict__ alpha,  // [COUT]
    float* __restrict__ y)            // [B][COUT][64][64]
{
    const int h = blockIdx.x;
    const int b = blockIdx.y;
    __shared__ float lds[3][CIN][66];   // rows h-1..h+1, w padded by 1 (zeros)
    const int t = threadIdx.x;

    for (int idx = t; idx < 3 * CIN * 64; idx += 512) {
        int r  = idx / (CIN * 64);
        int ci = (idx >> 6) % CIN;
        int w  = idx & 63;
        int hh = h + r - 1;
        float v = 0.f;
        if (hh >= 0 && hh < 64)
            v = x[((b * CIN + ci) * 64 + hh) * 64 + w];
        lds[r][ci][w + 1] = v;
    }
    if (t < 3 * CIN) {
        int r = t / CIN, ci = t % CIN;
        lds[r][ci][0]  = 0.f;
        lds[r][ci][65] = 0.f;
    }
    __syncthreads();

    const int w   = t & 63;
    const int cg  = __builtin_amdgcn_readfirstlane(t >> 6);  // wave-uniform 0..7
    const int co0 = cg * CPT;

    float acc[CPT];
#pragma unroll
    for (int i = 0; i < CPT; ++i) acc[i] = bias[co0 + i];

    for (int ci = 0; ci < CIN; ++ci) {
        float v[3][3];
#pragma unroll
        for (int ky = 0; ky < 3; ++ky) {
            v[ky][0] = lds[ky][ci][w];
            v[ky][1] = lds[ky][ci][w + 1];
            v[ky][2] = lds[ky][ci][w + 2];
        }
#pragma unroll
        for (int co = 0; co < CPT; ++co) {
            const float* wp = &wgt[((co0 + co) * CIN + ci) * 9];
            float a = acc[co];
            a = fmaf(wp[0], v[0][0], a);
            a = fmaf(wp[1], v[0][1], a);
            a = fmaf(wp[2], v[0][2], a);
            a = fmaf(wp[3], v[1][0], a);
            a = fmaf(wp[4], v[1][1], a);
            a = fmaf(wp[5], v[1][2], a);
            a = fmaf(wp[6], v[2][0], a);
            a = fmaf(wp[7], v[2][1], a);
            a = fmaf(wp[8], v[2][2], a);
            acc[co] = a;
        }
    }

#pragma unroll
    for (int co = 0; co < CPT; ++co) {
        float a  = acc[co];
        float al = alpha[co0 + co];
        float o  = (a > 0.f) ? a : al * a;
        y[((b * COUT + co0 + co) * 64 + h) * 64 + w] = o;
    }
}

// ---------------- fused 1x1-conv + softmax + upsample ----------------
// grid(2, 64, 8) = (cq, w, b); 512 threads = 8 waves: lane h = t&63, wave cg.
// Each thread handles 4 channels c = (cq*8+cg)*4 + cc at its (h, w) pixel.
__global__ __launch_bounds__(512, 4) void k_upsample(
    const float* __restrict__ f2,    // [B][32][64][64]
    const float* __restrict__ kpw,   // [2304][32]
    const float* __restrict__ kpb,   // [2304]
    const float* __restrict__ xlow,  // [B][64][64][64]
    float* __restrict__ out)         // [B][64][128][128]
{
    const int cq = blockIdx.x;
    const int w  = blockIdx.y;
    const int b  = blockIdx.z;
    __shared__ float F[32][64];      // F[ci][h] for this (b, w) column
    const int t = threadIdx.x;

    for (int idx = t; idx < 32 * 64; idx += 512) {
        int ci = idx >> 6, h = idx & 63;
        F[ci][h] = f2[((b * 32 + ci) * 64 + h) * 64 + w];
    }
    __syncthreads();

    const int h  = t & 63;
    const int cg = __builtin_amdgcn_readfirstlane(t >> 6);  // wave-uniform 0..7

    for (int cc = 0; cc < 4; ++cc) {
        const int c = (cq * 8 + cg) * 4 + cc;

        // mask rows for this c: rows c*36 .. c*36+35, each a K=32 dot
        float acc[36];
#pragma unroll
        for (int r = 0; r < 36; ++r) acc[r] = kpb[c * 36 + r];

        const float4* wp4 = (const float4*)(kpw + c * 36 * 32);
        for (int ci4 = 0; ci4 < 8; ++ci4) {
            float f0  = F[ci4 * 4 + 0][h];
            float f1  = F[ci4 * 4 + 1][h];
            float f2v = F[ci4 * 4 + 2][h];
            float f3  = F[ci4 * 4 + 3][h];
#pragma unroll
            for (int r = 0; r < 36; ++r) {
                float4 wv = wp4[r * 8 + ci4];
                acc[r] = fmaf(wv.x, f0,
                         fmaf(wv.y, f1,
                         fmaf(wv.z, f2v,
                         fmaf(wv.w, f3, acc[r]))));
            }
        }

        // 9 neighbors of x_low with edge clamp
        float neigh[9];
#pragma unroll
        for (int k = 0; k < 9; ++k) {
            int dy = k / 3 - 1, dx = k % 3 - 1;
            int hh = min(max(h + dy, 0), 63);
            int ww = min(max(w + dx, 0), 63);
            neigh[k] = xlow[((b * 64 + c) * 64 + hh) * 64 + ww];
        }

        // softmax over k per (p,q), weighted sum, transposed store
#pragma unroll
        for (int q = 0; q < 2; ++q) {
            float2 o2;
#pragma unroll
            for (int p = 0; p < 2; ++p) {
                const int pq = p * 2 + q;
                float m = acc[pq];
#pragma unroll
                for (int k = 1; k < 9; ++k) m = fmaxf(m, acc[k * 4 + pq]);
                float ssum = 0.f, ov = 0.f;
#pragma unroll
                for (int k = 0; k < 9; ++k) {
                    float e = __expf(acc[k * 4 + pq] - m);
                    ssum += e;
                    ov = fmaf(e, neigh[k], ov);
                }
                ((float*)&o2)[p] = ov / ssum;
            }
            // out[b][c][2w+q][2h+p]; p contiguous -> float2, lanes h -> coalesced
            *(float2*)&out[((b * 64 + c) * 128 + (2 * w + q)) * 128 + 2 * h] = o2;
        }
    }
}

extern "C" void kernel_launch(void* const* d_in, const int* in_sizes, int n_in,
                              void* d_out, int out_size, void* d_ws, size_t ws_size,
                              hipStream_t stream) {
    (void)in_sizes; (void)n_in; (void)out_size; (void)ws_size;
    const float* x_low = (const float*)d_in[0];
    const float* ctx   = (const float*)d_in[1];
    const float* c1_w  = (const float*)d_in[2];
    const float* c1_b  = (const float*)d_in[3];
    const float* p1_a  = (const float*)d_in[4];
    const float* c2_w  = (const float*)d_in[5];
    const float* c2_b  = (const float*)d_in[6];
    const float* p2_a  = (const float*)d_in[7];
    const float* kp_w  = (const float*)d_in[8];
    const float* kp_b  = (const float*)d_in[9];
    float* out = (float*)d_out;

    float* f1 = (float*)d_ws;                  // 8*64*64*64 floats = 8 MB
    float* f2 = f1 + 8 * 64 * 64 * 64;         // 8*32*64*64 floats = 4 MB

    k_conv3x3<64, 64, 8><<<dim3(64, 8), 512, 0, stream>>>(ctx, c1_w, c1_b, p1_a, f1);
    k_conv3x3<64, 32, 4><<<dim3(64, 8), 512, 0, stream>>>(f1, c2_w, c2_b, p2_a, f2);
    k_upsample<<<dim3(2, 64, 8), 512, 0, stream>>>(f2, kp_w, kp_b, x_low, out);
}

// Round 9
// 309.107 us; speedup vs baseline: 1.4382x; 1.1110x over previous
//
#include <hip/hip_runtime.h>

// Shapes fixed by setup_inputs: B=8, C=64, H=W=64, CTX=64, SF=2
// f1 = prelu(conv3x3(ctx)+b1)   : [8][64][64][64]   (ws)
// f2 = prelu(conv3x3(f1)+b2)    : [8][32][64][64]   (ws)
// out = fused 1x1conv(kp) + softmax(9 taps) + upsample (mask never materialized)
// Convs identical to R6 (passed). Upsample restructured: per-(p,q) 9-row
// accumulator (no spill), f2 column cached in regs, x_low column staged in LDS.

// ---------------- conv 3x3 + bias + prelu ----------------
// grid(64, 8) = (h, b); 512 threads = 8 waves: lane w = t&63, wave cg = t>>6.
template <int CIN, int COUT, int CPT>
__global__ __launch_bounds__(512, 4) void k_conv3x3(
    const float* __restrict__ x,      // [B][CIN][64][64]
    const float* __restrict__ wgt,    // [COUT][CIN][3][3]
    const float* __restrict__ bias,   // [COUT]
    const float* __restrict__ alpha,  // [COUT]
    float* __restrict__ y)            // [B][COUT][64][64]
{
    const int h = blockIdx.x;
    const int b = blockIdx.y;
    __shared__ float lds[3][CIN][66];   // rows h-1..h+1, w padded by 1 (zeros)
    const int t = threadIdx.x;

    for (int idx = t; idx < 3 * CIN * 64; idx += 512) {
        int r  = idx / (CIN * 64);
        int ci = (idx >> 6) % CIN;
        int w  = idx & 63;
        int hh = h + r - 1;
        float v = 0.f;
        if (hh >= 0 && hh < 64)
            v = x[((b * CIN + ci) * 64 + hh) * 64 + w];
        lds[r][ci][w + 1] = v;
    }
    if (t < 3 * CIN) {
        int r = t / CIN, ci = t % CIN;
        lds[r][ci][0]  = 0.f;
        lds[r][ci][65] = 0.f;
    }
    __syncthreads();

    const int w   = t & 63;
    const int cg  = __builtin_amdgcn_readfirstlane(t >> 6);  // wave-uniform 0..7
    const int co0 = cg * CPT;

    float acc[CPT];
#pragma unroll
    for (int i = 0; i < CPT; ++i) acc[i] = bias[co0 + i];

    for (int ci = 0; ci < CIN; ++ci) {
        float v[3][3];
#pragma unroll
        for (int ky = 0; ky < 3; ++ky) {
            v[ky][0] = lds[ky][ci][w];
            v[ky][1] = lds[ky][ci][w + 1];
            v[ky][2] = lds[ky][ci][w + 2];
        }
#pragma unroll
        for (int co = 0; co < CPT; ++co) {
            const float* wp = &wgt[((co0 + co) * CIN + ci) * 9];
            float a = acc[co];
            a = fmaf(wp[0], v[0][0], a);
            a = fmaf(wp[1], v[0][1], a);
            a = fmaf(wp[2], v[0][2], a);
            a = fmaf(wp[3], v[1][0], a);
            a = fmaf(wp[4], v[1][1], a);
            a = fmaf(wp[5], v[1][2], a);
            a = fmaf(wp[6], v[2][0], a);
            a = fmaf(wp[7], v[2][1], a);
            a = fmaf(wp[8], v[2][2], a);
            acc[co] = a;
        }
    }

#pragma unroll
    for (int co = 0; co < CPT; ++co) {
        float a  = acc[co];
        float al = alpha[co0 + co];
        float o  = (a > 0.f) ? a : al * a;
        y[((b * COUT + co0 + co) * 64 + h) * 64 + w] = o;
    }
}

// ---------------- fused 1x1-conv + softmax + upsample ----------------
// grid(2, 64, 8) = (cq, w, b); 512 threads = 8 waves: lane h = t&63, wave cg.
// Block covers channels cq*32 .. cq*32+31; each thread does 4 of them.
// Per channel, loop output taps (p,q): only 9 mask rows (r = k*4+pq) live
// at a time -> acc[9] in registers (was acc[36] -> scratch).
__global__ __launch_bounds__(512, 4) void k_upsample(
    const float* __restrict__ f2,    // [B][32][64][64]
    const float* __restrict__ kpw,   // [2304][32]
    const float* __restrict__ kpb,   // [2304]
    const float* __restrict__ xlow,  // [B][64][64][64]
    float* __restrict__ out)         // [B][64][128][128]
{
    const int cq = blockIdx.x;
    const int w  = blockIdx.y;
    const int b  = blockIdx.z;
    __shared__ float F[32][64];      // f2[ci][h] for this (b, w) column
    __shared__ float Xl[32][3][64];  // xlow[cq*32+ci][w-1+dx clamped][h]
    const int t = threadIdx.x;

    for (int idx = t; idx < 32 * 64; idx += 512) {
        int ci = idx >> 6, h = idx & 63;
        F[ci][h] = f2[((b * 32 + ci) * 64 + h) * 64 + w];
    }
    for (int idx = t; idx < 32 * 3 * 64; idx += 512) {
        int h = idx & 63, dx = (idx >> 6) % 3, ci = idx / 192;
        int ww = min(max(w + dx - 1, 0), 63);
        Xl[ci][dx][h] = xlow[((b * 64 + cq * 32 + ci) * 64 + h) * 64 + ww];
    }
    __syncthreads();

    const int h  = t & 63;
    const int cg = __builtin_amdgcn_readfirstlane(t >> 6);  // wave-uniform 0..7

    float fu[32];
#pragma unroll
    for (int ci = 0; ci < 32; ++ci) fu[ci] = F[ci][h];

    const int hm = max(h - 1, 0), hp = min(h + 1, 63);

    for (int cc = 0; cc < 4; ++cc) {
        const int c  = cq * 32 + cg * 4 + cc;   // global channel (wave-uniform)
        const int cl = cg * 4 + cc;             // local channel for Xl
        const float4* wp4 = (const float4*)(kpw + c * 36 * 32);
        const float*  bp  = kpb + c * 36;

#pragma unroll
        for (int q = 0; q < 2; ++q) {
            float o2[2];
#pragma unroll
            for (int p = 0; p < 2; ++p) {
                const int pq = p * 2 + q;
                float acc[9];
#pragma unroll
                for (int k = 0; k < 9; ++k) acc[k] = bp[k * 4 + pq];
#pragma unroll
                for (int ci4 = 0; ci4 < 8; ++ci4) {
                    float f0 = fu[ci4 * 4 + 0], f1 = fu[ci4 * 4 + 1];
                    float f2v = fu[ci4 * 4 + 2], f3 = fu[ci4 * 4 + 3];
#pragma unroll
                    for (int k = 0; k < 9; ++k) {
                        float4 wv = wp4[(k * 4 + pq) * 8 + ci4];
                        acc[k] = fmaf(wv.x, f0,
                                 fmaf(wv.y, f1,
                                 fmaf(wv.z, f2v,
                                 fmaf(wv.w, f3, acc[k]))));
                    }
                }
                float m = acc[0];
#pragma unroll
                for (int k = 1; k < 9; ++k) m = fmaxf(m, acc[k]);
                float s = 0.f, ov = 0.f;
#pragma unroll
                for (int k = 0; k < 9; ++k) {
                    const int dy = k / 3, dx = k % 3;
                    const int hh = (dy == 0) ? hm : (dy == 1 ? h : hp);
                    float e = __expf(acc[k] - m);
                    s += e;
                    ov = fmaf(e, Xl[cl][dx][hh], ov);
                }
                o2[p] = ov / s;
            }
            // out[b][c][2w+q][2h+p]; p contiguous -> float2, lanes h -> coalesced
            *(float2*)&out[((b * 64 + c) * 128 + (2 * w + q)) * 128 + 2 * h] =
                make_float2(o2[0], o2[1]);
        }
    }
}

extern "C" void kernel_launch(void* const* d_in, const int* in_sizes, int n_in,
                              void* d_out, int out_size, void* d_ws, size_t ws_size,
                              hipStream_t stream) {
    (void)in_sizes; (void)n_in; (void)out_size; (void)ws_size;
    const float* x_low = (const float*)d_in[0];
    const float* ctx   = (const float*)d_in[1];
    const float* c1_w  = (const float*)d_in[2];
    const float* c1_b  = (const float*)d_in[3];
    const float* p1_a  = (const float*)d_in[4];
    const float* c2_w  = (const float*)d_in[5];
    const float* c2_b  = (const float*)d_in[6];
    const float* p2_a  = (const float*)d_in[7];
    const float* kp_w  = (const float*)d_in[8];
    const float* kp_b  = (const float*)d_in[9];
    float* out = (float*)d_out;

    float* f1 = (float*)d_ws;                  // 8*64*64*64 floats = 8 MB
    float* f2 = f1 + 8 * 64 * 64 * 64;         // 8*32*64*64 floats = 4 MB

    k_conv3x3<64, 64, 8><<<dim3(64, 8), 512, 0, stream>>>(ctx, c1_w, c1_b, p1_a, f1);
    k_conv3x3<64, 32, 4><<<dim3(64, 8), 512, 0, stream>>>(f1, c2_w, c2_b, p2_a, f2);
    k_upsample<<<dim3(2, 64, 8), 512, 0, stream>>>(f2, kp_w, kp_b, x_low, out);
}